// Round 3
// baseline (1568.693 us; speedup 1.0000x reference)
//
#include <hip/hip_runtime.h>

typedef __bf16 bf16x8 __attribute__((ext_vector_type(8)));
typedef float f32x4 __attribute__((ext_vector_type(4)));

constexpr int E_ = 128, H_ = 4, HS_ = 32, L_ = 4, T_ = 512, V_ = 512, B_ = 64;
constexpr int M_ = B_ * T_; // 32768 rows

__device__ __forceinline__ float b2f(ushort u) {
    return __uint_as_float(((uint)u) << 16);
}
__device__ __forceinline__ ushort f2b(float f) {
    uint x = __float_as_uint(f);
    uint r = (x + 0x7fffu + ((x >> 16) & 1u)) >> 16;
    return (ushort)r;
}

struct F8 { float v[8]; };
__device__ __forceinline__ F8 unpack8(uint4 u) {
    F8 r;
    r.v[0] = __uint_as_float(u.x << 16); r.v[1] = __uint_as_float(u.x & 0xffff0000u);
    r.v[2] = __uint_as_float(u.y << 16); r.v[3] = __uint_as_float(u.y & 0xffff0000u);
    r.v[4] = __uint_as_float(u.z << 16); r.v[5] = __uint_as_float(u.z & 0xffff0000u);
    r.v[6] = __uint_as_float(u.w << 16); r.v[7] = __uint_as_float(u.w & 0xffff0000u);
    return r;
}

// ---------------- dtype detection + canonicalization ------------------------------
// ln1_g is identically 1.0. fp32 buffer -> first u32 = 0x3F800000;
// bf16 buffer -> first u32 = 0x3F803F80. Unambiguous.
__global__ void k_detect(const uint* __restrict__ ln1g_raw, int* __restrict__ flag) {
    if (threadIdx.x == 0 && blockIdx.x == 0)
        *flag = (ln1g_raw[0] == 0x3F800000u) ? 1 : 0;   // 1 = fp32 buffers
}

constexpr int kNSeg = 19;
constexpr int kOffs[kNSeg + 1] = {
    0, 65536, 131072, 196608, 262144, 327680, 393216, 393728, 394240, 394752,
    395264, 395776, 657920, 659968, 922112, 922624, 922752, 922880, 988416, 988928
};
constexpr int kTotal = 988928;

struct SrcPtrs { const void* p[kNSeg]; };

__global__ __launch_bounds__(256) void k_convert(SrcPtrs sp, const int* __restrict__ flag,
                                                 ushort* __restrict__ arena) {
    int gid = blockIdx.x * 256 + threadIdx.x;
    if (gid >= kTotal) return;
    int s = 0;
    #pragma unroll
    for (int i = 1; i < kNSeg; i++) if (gid >= kOffs[i]) s = i;
    int local = gid - kOffs[s];
    ushort v;
    if (*flag) v = f2b(((const float*)sp.p[s])[local]);
    else       v = ((const ushort*)sp.p[s])[local];
    arena[gid] = v;
}

// ---------------- prep: wq/wk/wv [L,H,E,HS] -> wqkvt [L][384][128] (k-contiguous) ---
__global__ void k_prep_qkv(const ushort* __restrict__ wq, const ushort* __restrict__ wk,
                           const ushort* __restrict__ wv, ushort* __restrict__ wt) {
    int gid = blockIdx.x * 256 + threadIdx.x; // L*384*128 = 196608
    if (gid >= L_ * 384 * E_) return;
    int e = gid & 127;
    int n = (gid >> 7) % 384;
    int l = gid / (384 * E_);
    int part = n >> 7, within = n & 127, hh = within >> 5, d = within & 31;
    const ushort* src = part == 0 ? wq : (part == 1 ? wk : wv);
    wt[gid] = src[(((size_t)(l * H_ + hh) * E_) + e) * HS_ + d];
}

// ---------------- embedding ---------------------------------------------------------
__global__ void k_embed(const int* __restrict__ idx, const ushort* __restrict__ tok,
                        const ushort* __restrict__ pos, float* __restrict__ x) {
    int gid = blockIdx.x * 256 + threadIdx.x; // exactly 32768*128
    int row = gid >> 7, e = gid & 127;
    int t = row & (T_ - 1);
    int id = idx[row];
    x[gid] = b2f(tok[id * E_ + e]) + b2f(pos[t * E_ + e]);
}

// ---------------- layernorm --------------------------------------------------------
__global__ __launch_bounds__(256) void k_ln(const float* __restrict__ x, const ushort* __restrict__ g,
                                            const ushort* __restrict__ beta, ushort* __restrict__ out) {
    int wave = threadIdx.x >> 6, lane = threadIdx.x & 63;
    int row = blockIdx.x * 4 + wave;
    const float* xr = x + (size_t)row * E_;
    float v0 = xr[lane], v1 = xr[lane + 64];
    float s = v0 + v1;
    #pragma unroll
    for (int m = 32; m; m >>= 1) s += __shfl_xor(s, m, 64);
    float mu = s * (1.0f / 128.0f);
    float d0 = v0 - mu, d1 = v1 - mu;
    float ss = d0 * d0 + d1 * d1;
    #pragma unroll
    for (int m = 32; m; m >>= 1) ss += __shfl_xor(ss, m, 64);
    float rstd = rsqrtf(ss * (1.0f / 128.0f) + 1e-5f);
    size_t o = (size_t)row * E_;
    out[o + lane]      = f2b(d0 * rstd * b2f(g[lane])      + b2f(beta[lane]));
    out[o + lane + 64] = f2b(d1 * rstd * b2f(g[lane + 64]) + b2f(beta[lane + 64]));
}

// ---------------- GEMM: C[M,N] = A[M,K] * W[N,K]^T ---------------------------------
// EPI: 0 = store bf16; 1 = +bias, dtype per *oflag; 2 = +bias,gelu bf16; 3 = +bias, fp32 +=
template<int EPI>
__global__ __launch_bounds__(256) void k_gemm(const ushort* __restrict__ A, const ushort* __restrict__ W,
                                              const ushort* __restrict__ bias, void* __restrict__ outp,
                                              const int* __restrict__ oflag, int K, int lda, int ldc) {
    int wid = threadIdx.x >> 6, lane = threadIdx.x & 63;
    int wr = wid >> 1, wc = wid & 1;
    int bm = blockIdx.x, bn = blockIdx.y;
    int r16 = lane & 15, kq = lane >> 4;
    const ushort* Abase = A + (size_t)(bm * 128 + wr * 64 + r16) * lda + kq * 8;
    const ushort* Wbase = W + (size_t)(bn * 128 + wc * 64 + r16) * K + kq * 8;
    bool f32out = false;
    if constexpr (EPI == 1) f32out = (*oflag != 0);
    f32x4 acc[4][4];
    #pragma unroll
    for (int i = 0; i < 4; i++)
        #pragma unroll
        for (int j = 0; j < 4; j++) acc[i][j] = (f32x4)0.0f;
    for (int k0 = 0; k0 < K; k0 += 32) {
        bf16x8 af[4], wf[4];
        #pragma unroll
        for (int mi = 0; mi < 4; mi++)
            af[mi] = *(const bf16x8*)(Abase + (size_t)mi * 16 * lda + k0);
        #pragma unroll
        for (int ni = 0; ni < 4; ni++)
            wf[ni] = *(const bf16x8*)(Wbase + (size_t)ni * 16 * K + k0);
        #pragma unroll
        for (int mi = 0; mi < 4; mi++)
            #pragma unroll
            for (int ni = 0; ni < 4; ni++)
                acc[mi][ni] = __builtin_amdgcn_mfma_f32_16x16x32_bf16(af[mi], wf[ni], acc[mi][ni], 0, 0, 0);
    }
    int orow0 = bm * 128 + wr * 64 + kq * 4;
    int ocol0 = bn * 128 + wc * 64 + r16;
    #pragma unroll
    for (int mi = 0; mi < 4; mi++) {
        #pragma unroll
        for (int ni = 0; ni < 4; ni++) {
            int col = ocol0 + ni * 16;
            float bv = 0.0f;
            if constexpr (EPI >= 1) bv = b2f(bias[col]);
            #pragma unroll
            for (int e = 0; e < 4; e++) {
                int row = orow0 + mi * 16 + e;
                float v = acc[mi][ni][e] + bv;
                if constexpr (EPI == 2) v = 0.5f * v * (1.0f + erff(v * 0.70710678118f));
                if constexpr (EPI == 3) {
                    ((float*)outp)[(size_t)row * ldc + col] += v;
                } else if constexpr (EPI == 1) {
                    if (f32out) ((float*)outp)[(size_t)row * ldc + col] = v;
                    else        ((ushort*)outp)[(size_t)row * ldc + col] = f2b(v);
                } else {
                    ((ushort*)outp)[(size_t)row * ldc + col] = f2b(v);
                }
            }
        }
    }
}

// ---------------- attention --------------------------------------------------------
__global__ __launch_bounds__(256) void k_attn(const ushort* __restrict__ qkv, ushort* __restrict__ o) {
    __shared__ float qlds[4][4][32];
    __shared__ float plds[4][4][512];
    int w = threadIdx.x >> 6, lane = threadIdx.x & 63;
    int quad = blockIdx.x * 4 + w;    // 0..32767
    int bh = quad >> 7;
    int qb = quad & 127;
    int b = bh >> 2, h = bh & 3;
    const ushort* base = qkv + (size_t)b * T_ * 384;
    const int qoff = h * 32, koff = 128 + h * 32, voff = 256 + h * 32;
    for (int ii = lane; ii < 128; ii += 64) {
        int r = ii >> 5, d = ii & 31;
        int t = qb + r * 128;
        qlds[w][r][d] = b2f(base[(size_t)t * 384 + qoff + d]);
    }
    __syncthreads();
    const float scale = 0.17677669529663687f;
    float p[4][8];
    float rden[4];
    #pragma unroll
    for (int r = 0; r < 4; r++)
        #pragma unroll
        for (int jj = 0; jj < 8; jj++) p[r][jj] = -1e30f;
    for (int jj = 0; jj < 8; jj++) {
        int j = lane + jj * 64;
        if (j > qb + 384) break;
        const ushort* kp = base + (size_t)j * 384 + koff;
        uint4 kk[4];
        #pragma unroll
        for (int c = 0; c < 4; c++) kk[c] = *(const uint4*)(kp + c * 8);
        float s0 = 0.f, s1 = 0.f, s2 = 0.f, s3 = 0.f;
        #pragma unroll
        for (int c = 0; c < 4; c++) {
            F8 kf = unpack8(kk[c]);
            #pragma unroll
            for (int d = 0; d < 8; d++) {
                float kd = kf.v[d];
                int dd = c * 8 + d;
                s0 = fmaf(qlds[w][0][dd], kd, s0);
                s1 = fmaf(qlds[w][1][dd], kd, s1);
                s2 = fmaf(qlds[w][2][dd], kd, s2);
                s3 = fmaf(qlds[w][3][dd], kd, s3);
            }
        }
        p[0][jj] = (j <= qb)       ? s0 * scale : -1e30f;
        p[1][jj] = (j <= qb + 128) ? s1 * scale : -1e30f;
        p[2][jj] = (j <= qb + 256) ? s2 * scale : -1e30f;
        p[3][jj] = s3 * scale;
    }
    #pragma unroll
    for (int r = 0; r < 4; r++) {
        float m = -1e30f;
        #pragma unroll
        for (int jj = 0; jj < 8; jj++) m = fmaxf(m, p[r][jj]);
        #pragma unroll
        for (int mk = 32; mk; mk >>= 1) m = fmaxf(m, __shfl_xor(m, mk, 64));
        float sum = 0.f;
        #pragma unroll
        for (int jj = 0; jj < 8; jj++) { float e = __expf(p[r][jj] - m); p[r][jj] = e; sum += e; }
        #pragma unroll
        for (int mk = 32; mk; mk >>= 1) sum += __shfl_xor(sum, mk, 64);
        rden[r] = 1.0f / sum;
    }
    #pragma unroll
    for (int r = 0; r < 4; r++)
        #pragma unroll
        for (int jj = 0; jj < 8; jj++)
            plds[w][r][lane + jj * 64] = p[r][jj];
    __syncthreads();
    int dg = lane & 3, js = lane >> 2;
    const ushort* vbase = base + voff + dg * 8;
    #pragma unroll
    for (int r = 0; r < 4; r++) {
        int tr = qb + (r << 7);
        float a[8];
        #pragma unroll
        for (int d = 0; d < 8; d++) a[d] = 0.f;
        for (int j = js; j <= tr; j += 16) {
            float pj = plds[w][r][j];
            uint4 vv = *(const uint4*)(vbase + (size_t)j * 384);
            F8 vf = unpack8(vv);
            #pragma unroll
            for (int d = 0; d < 8; d++) a[d] = fmaf(pj, vf.v[d], a[d]);
        }
        #pragma unroll
        for (int d = 0; d < 8; d++) {
            float v = a[d];
            v += __shfl_xor(v, 4, 64);
            v += __shfl_xor(v, 8, 64);
            v += __shfl_xor(v, 16, 64);
            v += __shfl_xor(v, 32, 64);
            a[d] = v * rden[r];
        }
        if (js == 0) {
            uint4 ov;
            ov.x = (uint)f2b(a[0]) | ((uint)f2b(a[1]) << 16);
            ov.y = (uint)f2b(a[2]) | ((uint)f2b(a[3]) << 16);
            ov.z = (uint)f2b(a[4]) | ((uint)f2b(a[5]) << 16);
            ov.w = (uint)f2b(a[6]) | ((uint)f2b(a[7]) << 16);
            *(uint4*)(o + (size_t)(b * T_ + tr) * 128 + h * 32 + dg * 8) = ov;
        }
    }
}

extern "C" void kernel_launch(void* const* d_in, const int* in_sizes, int n_in,
                              void* d_out, int out_size, void* d_ws, size_t ws_size,
                              hipStream_t stream) {
    const int* idx = (const int*)d_in[0];

    // ws layout: x fp32 [0,16M); h bf16 [16M,24M); wqkvt [24M,+384K);
    //            arena bf16 [25M,+1.93M); flag int @ 27M.   (<28 MB total)
    char* ws = (char*)d_ws;
    float*  x     = (float*) (ws + 0);
    ushort* h     = (ushort*)(ws + (16u << 20));
    ushort* wqkvt = (ushort*)(ws + (24u << 20));
    ushort* arena = (ushort*)(ws + (25u << 20));
    int*    flag  = (int*)   (ws + (27u << 20));

    // d_out scratch: qkv [32768x384] bf16 @ [0,24M); o [32768x128] bf16 @ [24M,32M);
    // mid [32768x512] bf16 @ [0,32M). All dead before the final head GEMM rewrites d_out.
    ushort* qkv = (ushort*)d_out;
    ushort* o   = (ushort*)d_out + (12u << 20);
    ushort* mid = (ushort*)d_out;

    const ushort* tok    = arena + kOffs[0];
    const ushort* pos    = arena + kOffs[1];
    const ushort* wqp    = arena + kOffs[2];
    const ushort* wkp    = arena + kOffs[3];
    const ushort* wvp    = arena + kOffs[4];
    const ushort* w_proj = arena + kOffs[5];
    const ushort* b_proj = arena + kOffs[6];
    const ushort* ln1_g  = arena + kOffs[7];
    const ushort* ln1_b  = arena + kOffs[8];
    const ushort* ln2_g  = arena + kOffs[9];
    const ushort* ln2_b  = arena + kOffs[10];
    const ushort* w1     = arena + kOffs[11];
    const ushort* b1     = arena + kOffs[12];
    const ushort* w2     = arena + kOffs[13];
    const ushort* b2     = arena + kOffs[14];
    const ushort* lnf_g  = arena + kOffs[15];
    const ushort* lnf_b  = arena + kOffs[16];
    const ushort* w_head = arena + kOffs[17];
    const ushort* b_head = arena + kOffs[18];

    k_detect<<<1, 64, 0, stream>>>((const uint*)d_in[8], flag);
    SrcPtrs sp;
    for (int i = 0; i < kNSeg; i++) sp.p[i] = d_in[i + 1];
    k_convert<<<(kTotal + 255) / 256, 256, 0, stream>>>(sp, flag, arena);

    k_prep_qkv<<<768, 256, 0, stream>>>(wqp, wkp, wvp, wqkvt);
    k_embed<<<M_ * E_ / 256, 256, 0, stream>>>(idx, tok, pos, x);
    for (int l = 0; l < L_; l++) {
        k_ln<<<M_ / 4, 256, 0, stream>>>(x, ln1_g + l * E_, ln1_b + l * E_, h);
        k_gemm<0><<<dim3(M_ / 128, 3), 256, 0, stream>>>(h, wqkvt + (size_t)l * 384 * E_, nullptr, qkv, nullptr, 128, 128, 384);
        k_attn<<<M_ / 4, 256, 0, stream>>>(qkv, o);
        k_gemm<3><<<dim3(M_ / 128, 1), 256, 0, stream>>>(o, w_proj + (size_t)l * E_ * E_, b_proj + l * E_, x, nullptr, 128, 128, 128);
        k_ln<<<M_ / 4, 256, 0, stream>>>(x, ln2_g + l * E_, ln2_b + l * E_, h);
        k_gemm<2><<<dim3(M_ / 128, 4), 256, 0, stream>>>(h, w1 + (size_t)l * 4 * E_ * E_, b1 + l * 4 * E_, mid, nullptr, 128, 128, 512);
        k_gemm<3><<<dim3(M_ / 128, 1), 256, 0, stream>>>(mid, w2 + (size_t)l * E_ * 4 * E_, b2 + l * E_, x, nullptr, 512, 512, 128);
    }
    k_ln<<<M_ / 4, 256, 0, stream>>>(x, lnf_g, lnf_b, h);
    k_gemm<1><<<dim3(M_ / 128, 4), 256, 0, stream>>>(h, w_head, b_head, d_out, flag, 128, 128, 512);
}

// Round 5
// 758.241 us; speedup vs baseline: 2.0689x; 2.0689x over previous
//
#include <hip/hip_runtime.h>

typedef __bf16 bf16x8 __attribute__((ext_vector_type(8)));
typedef __bf16 bf16x2 __attribute__((ext_vector_type(2)));
typedef float f32x4 __attribute__((ext_vector_type(4)));

constexpr int E_ = 128, H_ = 4, HS_ = 32, L_ = 4, T_ = 512, V_ = 512, B_ = 64;
constexpr int M_ = B_ * T_; // 32768 rows

__device__ __forceinline__ float b2f(ushort u) {
    return __uint_as_float(((uint)u) << 16);
}
__device__ __forceinline__ ushort f2b(float f) {
    uint x = __float_as_uint(f);
    uint r = (x + 0x7fffu + ((x >> 16) & 1u)) >> 16;
    return (ushort)r;
}
__device__ __forceinline__ uint packbf(float a, float b) {
    bf16x2 t; t[0] = (__bf16)a; t[1] = (__bf16)b;
    return __builtin_bit_cast(uint, t);
}

// ---------------- dtype detection + canonicalization ------------------------------
// ln1_g is identically 1.0. fp32 buffer -> first u32 = 0x3F800000;
// bf16 buffer -> first u32 = 0x3F803F80. Unambiguous.
__global__ void k_detect(const uint* __restrict__ ln1g_raw, int* __restrict__ flag) {
    if (threadIdx.x == 0 && blockIdx.x == 0)
        *flag = (ln1g_raw[0] == 0x3F800000u) ? 1 : 0;   // 1 = fp32 buffers
}

constexpr int kNSeg = 19;
constexpr int kOffs[kNSeg + 1] = {
    0, 65536, 131072, 196608, 262144, 327680, 393216, 393728, 394240, 394752,
    395264, 395776, 657920, 659968, 922112, 922624, 922752, 922880, 988416, 988928
};
constexpr int kTotal = 988928;

struct SrcPtrs { const void* p[kNSeg]; };

__global__ __launch_bounds__(256) void k_convert(SrcPtrs sp, const int* __restrict__ flag,
                                                 ushort* __restrict__ arena) {
    int gid = blockIdx.x * 256 + threadIdx.x;
    if (gid >= kTotal) return;
    int s = 0;
    #pragma unroll
    for (int i = 1; i < kNSeg; i++) if (gid >= kOffs[i]) s = i;
    int local = gid - kOffs[s];
    ushort v;
    if (*flag) v = f2b(((const float*)sp.p[s])[local]);
    else       v = ((const ushort*)sp.p[s])[local];
    arena[gid] = v;
}

// ---------------- prep: wq/wk/wv [L,H,E,HS] -> wqkvt [L][384][128] (k-contiguous) ---
__global__ void k_prep_qkv(const ushort* __restrict__ wq, const ushort* __restrict__ wk,
                           const ushort* __restrict__ wv, ushort* __restrict__ wt) {
    int gid = blockIdx.x * 256 + threadIdx.x; // L*384*128 = 196608
    if (gid >= L_ * 384 * E_) return;
    int e = gid & 127;
    int n = (gid >> 7) % 384;
    int l = gid / (384 * E_);
    int part = n >> 7, within = n & 127, hh = within >> 5, d = within & 31;
    const ushort* src = part == 0 ? wq : (part == 1 ? wk : wv);
    wt[gid] = src[(((size_t)(l * H_ + hh) * E_) + e) * HS_ + d];
}

// ---------------- embedding ---------------------------------------------------------
__global__ void k_embed(const int* __restrict__ idx, const ushort* __restrict__ tok,
                        const ushort* __restrict__ pos, float* __restrict__ x) {
    int gid = blockIdx.x * 256 + threadIdx.x; // exactly 32768*128
    int row = gid >> 7, e = gid & 127;
    int t = row & (T_ - 1);
    int id = idx[row];
    x[gid] = b2f(tok[id * E_ + e]) + b2f(pos[t * E_ + e]);
}

// ---------------- layernorm --------------------------------------------------------
__global__ __launch_bounds__(256) void k_ln(const float* __restrict__ x, const ushort* __restrict__ g,
                                            const ushort* __restrict__ beta, ushort* __restrict__ out) {
    int wave = threadIdx.x >> 6, lane = threadIdx.x & 63;
    int row = blockIdx.x * 4 + wave;
    const float* xr = x + (size_t)row * E_;
    float v0 = xr[lane], v1 = xr[lane + 64];
    float s = v0 + v1;
    #pragma unroll
    for (int m = 32; m; m >>= 1) s += __shfl_xor(s, m, 64);
    float mu = s * (1.0f / 128.0f);
    float d0 = v0 - mu, d1 = v1 - mu;
    float ss = d0 * d0 + d1 * d1;
    #pragma unroll
    for (int m = 32; m; m >>= 1) ss += __shfl_xor(ss, m, 64);
    float rstd = rsqrtf(ss * (1.0f / 128.0f) + 1e-5f);
    size_t o = (size_t)row * E_;
    out[o + lane]      = f2b(d0 * rstd * b2f(g[lane])      + b2f(beta[lane]));
    out[o + lane + 64] = f2b(d1 * rstd * b2f(g[lane + 64]) + b2f(beta[lane + 64]));
}

// ---------------- GEMM: C[M,N] = A[M,K] * W[N,K]^T ---------------------------------
// EPI: 0 = store bf16; 1 = +bias, dtype per *oflag; 2 = +bias,gelu bf16; 3 = +bias, fp32 +=
//      4 = qkv special: bn<2 -> qk store (ldc); bn==2 -> transposed V store to outp2 (vt)
template<int EPI>
__global__ __launch_bounds__(256) void k_gemm(const ushort* __restrict__ A, const ushort* __restrict__ W,
                                              const ushort* __restrict__ bias, void* __restrict__ outp,
                                              void* __restrict__ outp2,
                                              const int* __restrict__ oflag, int K, int lda, int ldc) {
    int wid = threadIdx.x >> 6, lane = threadIdx.x & 63;
    int wr = wid >> 1, wc = wid & 1;
    int bm = blockIdx.x, bn = blockIdx.y;
    int r16 = lane & 15, kq = lane >> 4;
    const ushort* Abase = A + (size_t)(bm * 128 + wr * 64 + r16) * lda + kq * 8;
    const ushort* Wbase = W + (size_t)(bn * 128 + wc * 64 + r16) * K + kq * 8;
    bool f32out = false;
    if constexpr (EPI == 1) f32out = (*oflag != 0);
    f32x4 acc[4][4];
    #pragma unroll
    for (int i = 0; i < 4; i++)
        #pragma unroll
        for (int j = 0; j < 4; j++) acc[i][j] = (f32x4)0.0f;
    for (int k0 = 0; k0 < K; k0 += 32) {
        bf16x8 af[4], wf[4];
        #pragma unroll
        for (int mi = 0; mi < 4; mi++)
            af[mi] = *(const bf16x8*)(Abase + (size_t)mi * 16 * lda + k0);
        #pragma unroll
        for (int ni = 0; ni < 4; ni++)
            wf[ni] = *(const bf16x8*)(Wbase + (size_t)ni * 16 * K + k0);
        #pragma unroll
        for (int mi = 0; mi < 4; mi++)
            #pragma unroll
            for (int ni = 0; ni < 4; ni++)
                acc[mi][ni] = __builtin_amdgcn_mfma_f32_16x16x32_bf16(af[mi], wf[ni], acc[mi][ni], 0, 0, 0);
    }
    // C/D layout: col = lane&15 (operand-B dim), row = (lane>>4)*4 + reg (operand-A dim)
    int orow0 = bm * 128 + wr * 64 + kq * 4;
    int ocol0 = bn * 128 + wc * 64 + r16;
    if constexpr (EPI == 4) {
        if (bn == 2) {
            // V part: cols 256..383 -> vt[bh][d][t]; 4 consecutive accum rows = 4 consecutive t
            ushort* vt = (ushort*)outp2;
            #pragma unroll
            for (int mi = 0; mi < 4; mi++) {
                int row0 = orow0 + mi * 16;
                int bb = row0 >> 9, tt = row0 & 511;
                #pragma unroll
                for (int ni = 0; ni < 4; ni++) {
                    int vd = (ocol0 - 256) + ni * 16;      // 0..127 = h*32 + d
                    int hh = vd >> 5, dd = vd & 31;
                    ushort4 pk;
                    pk.x = f2b(acc[mi][ni][0]); pk.y = f2b(acc[mi][ni][1]);
                    pk.z = f2b(acc[mi][ni][2]); pk.w = f2b(acc[mi][ni][3]);
                    *(ushort4*)(vt + (((size_t)(bb * 4 + hh) * 32 + dd) << 9) + tt) = pk;
                }
            }
            return;
        }
        // qk part falls through to normal bf16 store below
    }
    #pragma unroll
    for (int mi = 0; mi < 4; mi++) {
        #pragma unroll
        for (int ni = 0; ni < 4; ni++) {
            int col = ocol0 + ni * 16;
            float bv = 0.0f;
            if constexpr (EPI >= 1 && EPI <= 3) bv = b2f(bias[col]);
            #pragma unroll
            for (int e = 0; e < 4; e++) {
                int row = orow0 + mi * 16 + e;
                float v = acc[mi][ni][e] + bv;
                if constexpr (EPI == 2) v = 0.5f * v * (1.0f + erff(v * 0.70710678118f));
                if constexpr (EPI == 3) {
                    ((float*)outp)[(size_t)row * ldc + col] += v;
                } else if constexpr (EPI == 1) {
                    if (f32out) ((float*)outp)[(size_t)row * ldc + col] = v;
                    else        ((ushort*)outp)[(size_t)row * ldc + col] = f2b(v);
                } else {
                    ((ushort*)outp)[(size_t)row * ldc + col] = f2b(v);
                }
            }
        }
    }
}

// ---------------- MFMA flash attention --------------------------------------------
// qk: [M, 256] bf16 (cols 0..127 = q heads, 128..255 = k heads), row = b*512+t
// vt: [256 bh][32 d][512 t] bf16   (V transposed, from GEMM epilogue)
// o : [M, 128] bf16
// Swapped QK^T: S^T tile = mfma(A=K, B=Q) -> lane owns q = lane&15.
// Softmax stats shared across the 4-lane q-group (xor 16, 32).
// PV: O^T tile = mfma(A=V^T, B=P^T) -> O accumulator also q = lane&15.
__global__ __launch_bounds__(256) void k_attn_mfma(const ushort* __restrict__ qk,
                                                   const ushort* __restrict__ vt,
                                                   ushort* __restrict__ o) {
    int lane = threadIdx.x & 63, w = threadIdx.x >> 6;
    int qs = blockIdx.x, bh = blockIdx.y;
    int b = bh >> 2, h = bh & 3;
    int r16 = lane & 15, g = lane >> 4;
    int qbase = qs * 64 + w * 16;
    int qmax = qbase + 15;
    int myq = qbase + r16;
    const ushort* qkbase = qk + (size_t)b * 512 * 256;
    bf16x8 qf = *(const bf16x8*)(qkbase + (size_t)(qbase + r16) * 256 + h * 32 + g * 8);
    const ushort* kptr = qkbase + 128 + h * 32 + g * 8;          // + j*256
    const ushort* vbase = vt + ((size_t)bh * 32) * 512;           // rows d, stride 512
    f32x4 o0 = (f32x4)0.0f, o1 = (f32x4)0.0f;
    float m2 = -INFINITY, l = 0.0f;
    const float SC = 0.2550348637f;   // log2(e) / sqrt(32)
    for (int j0 = 0; j0 <= qmax; j0 += 32) {
        bf16x8 kf0 = *(const bf16x8*)(kptr + (size_t)(j0 + r16) * 256);
        bf16x8 kf1 = *(const bf16x8*)(kptr + (size_t)(j0 + 16 + r16) * 256);
        f32x4 s0 = __builtin_amdgcn_mfma_f32_16x16x32_bf16(kf0, qf, (f32x4)0.0f, 0, 0, 0);
        f32x4 s1 = __builtin_amdgcn_mfma_f32_16x16x32_bf16(kf1, qf, (f32x4)0.0f, 0, 0, 0);
        // per-lane j = j0 + 16*tile + 4*g + e ; mask j > myq
        float sv[8];
        #pragma unroll
        for (int e = 0; e < 4; e++) {
            int ja = j0 + 4 * g + e;
            sv[e]     = (ja      <= myq) ? s0[e] * SC : -INFINITY;
            sv[4 + e] = (ja + 16 <= myq) ? s1[e] * SC : -INFINITY;
        }
        float pm = sv[0];
        #pragma unroll
        for (int i = 1; i < 8; i++) pm = fmaxf(pm, sv[i]);
        // reduce max across the 4 lanes sharing this q (bits 4,5 of lane)
        pm = fmaxf(pm, __shfl_xor(pm, 16, 64));
        pm = fmaxf(pm, __shfl_xor(pm, 32, 64));
        float mn = fmaxf(m2, pm);           // finite from chunk 0 onward (j=0 unmasked)
        float c = exp2f(m2 - mn);           // first iter: exp2(-inf)=0
        float p[8], ps = 0.0f;
        #pragma unroll
        for (int i = 0; i < 8; i++) { p[i] = exp2f(sv[i] - mn); ps += p[i]; }
        ps += __shfl_xor(ps, 16, 64);
        ps += __shfl_xor(ps, 32, 64);
        l = l * c + ps;
        #pragma unroll
        for (int e = 0; e < 4; e++) { o0[e] *= c; o1[e] *= c; }
        m2 = mn;
        // relayout P (S^T C-layout) -> B-fragment (lane g holds P[q=r16][j = g*8..g*8+8])
        uint pk00 = packbf(p[0], p[1]), pk01 = packbf(p[2], p[3]);
        uint pk10 = packbf(p[4], p[5]), pk11 = packbf(p[6], p[7]);
        int ga = ((g & 1) << 5) + r16;   // src lane: group (g&1)*2, same q
        int gb = ga + 16;                // group (g&1)*2+1
        uint A0 = (uint)__shfl((int)pk00, ga), A1 = (uint)__shfl((int)pk01, ga);
        uint C0 = (uint)__shfl((int)pk00, gb), C1 = (uint)__shfl((int)pk01, gb);
        uint B0 = (uint)__shfl((int)pk10, ga), B1 = (uint)__shfl((int)pk11, ga);
        uint D0 = (uint)__shfl((int)pk10, gb), D1 = (uint)__shfl((int)pk11, gb);
        bool hi2 = g >= 2;
        uint4 pr;
        pr.x = hi2 ? B0 : A0; pr.y = hi2 ? B1 : A1;
        pr.z = hi2 ? D0 : C0; pr.w = hi2 ? D1 : C1;
        bf16x8 pf = __builtin_bit_cast(bf16x8, pr);
        bf16x8 vf0 = *(const bf16x8*)(vbase + (size_t)r16 * 512 + j0 + g * 8);
        bf16x8 vf1 = *(const bf16x8*)(vbase + (size_t)(16 + r16) * 512 + j0 + g * 8);
        o0 = __builtin_amdgcn_mfma_f32_16x16x32_bf16(vf0, pf, o0, 0, 0, 0);
        o1 = __builtin_amdgcn_mfma_f32_16x16x32_bf16(vf1, pf, o1, 0, 0, 0);
    }
    float inv = 1.0f / l;
    ushort4 w0, w1;
    w0.x = f2b(o0[0] * inv); w0.y = f2b(o0[1] * inv);
    w0.z = f2b(o0[2] * inv); w0.w = f2b(o0[3] * inv);
    w1.x = f2b(o1[0] * inv); w1.y = f2b(o1[1] * inv);
    w1.z = f2b(o1[2] * inv); w1.w = f2b(o1[3] * inv);
    // O^T C-layout: col q = lane&15, row d = 16*tile + 4g + e (4 consecutive d)
    size_t orow = (size_t)(b * 512 + qbase + r16) * 128 + h * 32;
    *(ushort4*)(o + orow + g * 4)      = w0;
    *(ushort4*)(o + orow + 16 + g * 4) = w1;
}

extern "C" void kernel_launch(void* const* d_in, const int* in_sizes, int n_in,
                              void* d_out, int out_size, void* d_ws, size_t ws_size,
                              hipStream_t stream) {
    const int* idx = (const int*)d_in[0];

    // ws layout: x fp32 [0,16M); h bf16 [16M,24M); wqkvt [24M,+384K);
    //            arena bf16 [25M,+1.93M); flag int @ 27M.   (<28 MB total)
    char* ws = (char*)d_ws;
    float*  x     = (float*) (ws + 0);
    ushort* h     = (ushort*)(ws + (16u << 20));
    ushort* wqkvt = (ushort*)(ws + (24u << 20));
    ushort* arena = (ushort*)(ws + (25u << 20));
    int*    flag  = (int*)   (ws + (27u << 20));

    // d_out scratch (32MB): qk [M,256] bf16 @ [0,16M); o [M,128] @ [16M,24M);
    // vt [256][32][512] @ [24M,32M); mid [M,512] @ [0,32M) overlays all after attn+proj.
    ushort* qkv = (ushort*)d_out;
    ushort* o   = (ushort*)d_out + (8u << 20);
    ushort* vt  = (ushort*)d_out + (12u << 20);
    ushort* mid = (ushort*)d_out;

    const ushort* tok    = arena + kOffs[0];
    const ushort* pos    = arena + kOffs[1];
    const ushort* wqp    = arena + kOffs[2];
    const ushort* wkp    = arena + kOffs[3];
    const ushort* wvp    = arena + kOffs[4];
    const ushort* w_proj = arena + kOffs[5];
    const ushort* b_proj = arena + kOffs[6];
    const ushort* ln1_g  = arena + kOffs[7];
    const ushort* ln1_b  = arena + kOffs[8];
    const ushort* ln2_g  = arena + kOffs[9];
    const ushort* ln2_b  = arena + kOffs[10];
    const ushort* w1     = arena + kOffs[11];
    const ushort* b1     = arena + kOffs[12];
    const ushort* w2     = arena + kOffs[13];
    const ushort* b2     = arena + kOffs[14];
    const ushort* lnf_g  = arena + kOffs[15];
    const ushort* lnf_b  = arena + kOffs[16];
    const ushort* w_head = arena + kOffs[17];
    const ushort* b_head = arena + kOffs[18];

    k_detect<<<1, 64, 0, stream>>>((const uint*)d_in[8], flag);
    SrcPtrs sp;
    for (int i = 0; i < kNSeg; i++) sp.p[i] = d_in[i + 1];
    k_convert<<<(kTotal + 255) / 256, 256, 0, stream>>>(sp, flag, arena);

    k_prep_qkv<<<768, 256, 0, stream>>>(wqp, wkp, wvp, wqkvt);
    k_embed<<<M_ * E_ / 256, 256, 0, stream>>>(idx, tok, pos, x);
    for (int l = 0; l < L_; l++) {
        k_ln<<<M_ / 4, 256, 0, stream>>>(x, ln1_g + l * E_, ln1_b + l * E_, h);
        k_gemm<4><<<dim3(M_ / 128, 3), 256, 0, stream>>>(h, wqkvt + (size_t)l * 384 * E_, nullptr, qkv, vt, nullptr, 128, 128, 256);
        k_attn_mfma<<<dim3(8, 256), 256, 0, stream>>>(qkv, vt, o);
        k_gemm<3><<<dim3(M_ / 128, 1), 256, 0, stream>>>(o, w_proj + (size_t)l * E_ * E_, b_proj + l * E_, x, nullptr, nullptr, 128, 128, 128);
        k_ln<<<M_ / 4, 256, 0, stream>>>(x, ln2_g + l * E_, ln2_b + l * E_, h);
        k_gemm<2><<<dim3(M_ / 128, 4), 256, 0, stream>>>(h, w1 + (size_t)l * 4 * E_ * E_, b1 + l * 4 * E_, mid, nullptr, nullptr, 128, 128, 512);
        k_gemm<3><<<dim3(M_ / 128, 1), 256, 0, stream>>>(mid, w2 + (size_t)l * E_ * 4 * E_, b2 + l * E_, x, nullptr, nullptr, 512, 512, 128);
    }
    k_ln<<<M_ / 4, 256, 0, stream>>>(x, lnf_g, lnf_b, h);
    k_gemm<1><<<dim3(M_ / 128, 4), 256, 0, stream>>>(h, w_head, b_head, d_out, nullptr, flag, 128, 128, 512);
}

// Round 6
// 524.587 us; speedup vs baseline: 2.9903x; 1.4454x over previous
//
#include <hip/hip_runtime.h>

typedef __bf16 bf16x8 __attribute__((ext_vector_type(8)));
typedef __bf16 bf16x2 __attribute__((ext_vector_type(2)));
typedef float f32x4 __attribute__((ext_vector_type(4)));

constexpr int E_ = 128, H_ = 4, HS_ = 32, L_ = 4, T_ = 512, V_ = 512, B_ = 64;
constexpr int M_ = B_ * T_; // 32768 rows

__device__ __forceinline__ float b2f(ushort u) {
    return __uint_as_float(((uint)u) << 16);
}
__device__ __forceinline__ ushort f2b(float f) {
    uint x = __float_as_uint(f);
    uint r = (x + 0x7fffu + ((x >> 16) & 1u)) >> 16;
    return (ushort)r;
}
__device__ __forceinline__ uint packbf(float a, float b) {
    bf16x2 t; t[0] = (__bf16)a; t[1] = (__bf16)b;
    return __builtin_bit_cast(uint, t);
}

// ---------------- dtype detection + canonicalization ------------------------------
__global__ void k_detect(const uint* __restrict__ ln1g_raw, int* __restrict__ flag) {
    if (threadIdx.x == 0 && blockIdx.x == 0)
        *flag = (ln1g_raw[0] == 0x3F800000u) ? 1 : 0;   // 1 = fp32 buffers
}

constexpr int kNSeg = 19;
constexpr int kOffs[kNSeg + 1] = {
    0, 65536, 131072, 196608, 262144, 327680, 393216, 393728, 394240, 394752,
    395264, 395776, 657920, 659968, 922112, 922624, 922752, 922880, 988416, 988928
};
constexpr int kTotal = 988928;

struct SrcPtrs { const void* p[kNSeg]; };

__global__ __launch_bounds__(256) void k_convert(SrcPtrs sp, const int* __restrict__ flag,
                                                 ushort* __restrict__ arena) {
    int gid = blockIdx.x * 256 + threadIdx.x;
    if (gid >= kTotal) return;
    int s = 0;
    #pragma unroll
    for (int i = 1; i < kNSeg; i++) if (gid >= kOffs[i]) s = i;
    int local = gid - kOffs[s];
    ushort v;
    if (*flag) v = f2b(((const float*)sp.p[s])[local]);
    else       v = ((const ushort*)sp.p[s])[local];
    arena[gid] = v;
}

// ---------------- prep: wq/wk/wv [L,H,E,HS] -> wqkvt [L][384][128] (k-contiguous) ---
__global__ void k_prep_qkv(const ushort* __restrict__ wq, const ushort* __restrict__ wk,
                           const ushort* __restrict__ wv, ushort* __restrict__ wt) {
    int gid = blockIdx.x * 256 + threadIdx.x; // L*384*128 = 196608
    if (gid >= L_ * 384 * E_) return;
    int e = gid & 127;
    int n = (gid >> 7) % 384;
    int l = gid / (384 * E_);
    int part = n >> 7, within = n & 127, hh = within >> 5, d = within & 31;
    const ushort* src = part == 0 ? wq : (part == 1 ? wk : wv);
    wt[gid] = src[(((size_t)(l * H_ + hh) * E_) + e) * HS_ + d];
}

// ---------------- embedding + LN1(layer0): x = tok[idx]+pos; h = LN(x) -------------
__global__ __launch_bounds__(256) void k_embed_ln(const int* __restrict__ idx,
                                                  const ushort* __restrict__ tok,
                                                  const ushort* __restrict__ pos,
                                                  const ushort* __restrict__ g,
                                                  const ushort* __restrict__ beta,
                                                  float* __restrict__ x, ushort* __restrict__ h) {
    int wave = threadIdx.x >> 6, lane = threadIdx.x & 63;
    int row = blockIdx.x * 4 + wave;
    int t = row & (T_ - 1);
    int id = idx[row];
    float v0 = b2f(tok[id * E_ + lane])      + b2f(pos[t * E_ + lane]);
    float v1 = b2f(tok[id * E_ + lane + 64]) + b2f(pos[t * E_ + lane + 64]);
    size_t o = (size_t)row * E_;
    x[o + lane] = v0; x[o + lane + 64] = v1;
    float s = v0 + v1;
    #pragma unroll
    for (int m = 32; m; m >>= 1) s += __shfl_xor(s, m, 64);
    float mu = s * (1.0f / 128.0f);
    float d0 = v0 - mu, d1 = v1 - mu;
    float ss = d0 * d0 + d1 * d1;
    #pragma unroll
    for (int m = 32; m; m >>= 1) ss += __shfl_xor(ss, m, 64);
    float rstd = rsqrtf(ss * (1.0f / 128.0f) + 1e-5f);
    h[o + lane]      = f2b(d0 * rstd * b2f(g[lane])      + b2f(beta[lane]));
    h[o + lane + 64] = f2b(d1 * rstd * b2f(g[lane + 64]) + b2f(beta[lane + 64]));
}

// ---------------- GEMM: C[M,N] = A[M,K] * W[N,K]^T ---------------------------------
// EPI: 1 = +bias, dtype per *oflag (head)
//      2 = +bias, exact gelu, bf16 (mlp1)
//      4 = qkv: bn<2 -> qk store; bn==2 -> transposed V store to outp2 (vt)
//      5 = +bias, x += v (fp32, outp), then h = LN(x; lng,lnb) bf16 (outp2). N must be 128, bn==0.
template<int EPI>
__global__ __launch_bounds__(256) void k_gemm(const ushort* __restrict__ A, const ushort* __restrict__ W,
                                              const ushort* __restrict__ bias, void* __restrict__ outp,
                                              void* __restrict__ outp2,
                                              const ushort* __restrict__ lng, const ushort* __restrict__ lnb,
                                              const int* __restrict__ oflag, int K, int lda, int ldc) {
    int wid = threadIdx.x >> 6, lane = threadIdx.x & 63;
    int wr = wid >> 1, wc = wid & 1;
    int bm = blockIdx.x, bn = blockIdx.y;
    int r16 = lane & 15, kq = lane >> 4;
    const ushort* Abase = A + (size_t)(bm * 128 + wr * 64 + r16) * lda + kq * 8;
    const ushort* Wbase = W + (size_t)(bn * 128 + wc * 64 + r16) * K + kq * 8;
    bool f32out = false;
    if constexpr (EPI == 1) f32out = (*oflag != 0);
    f32x4 acc[4][4];
    #pragma unroll
    for (int i = 0; i < 4; i++)
        #pragma unroll
        for (int j = 0; j < 4; j++) acc[i][j] = (f32x4)0.0f;
    for (int k0 = 0; k0 < K; k0 += 32) {
        bf16x8 af[4], wf[4];
        #pragma unroll
        for (int mi = 0; mi < 4; mi++)
            af[mi] = *(const bf16x8*)(Abase + (size_t)mi * 16 * lda + k0);
        #pragma unroll
        for (int ni = 0; ni < 4; ni++)
            wf[ni] = *(const bf16x8*)(Wbase + (size_t)ni * 16 * K + k0);
        #pragma unroll
        for (int mi = 0; mi < 4; mi++)
            #pragma unroll
            for (int ni = 0; ni < 4; ni++)
                acc[mi][ni] = __builtin_amdgcn_mfma_f32_16x16x32_bf16(af[mi], wf[ni], acc[mi][ni], 0, 0, 0);
    }
    // C/D layout: col = lane&15 (B dim), row = (lane>>4)*4 + reg (A dim)
    int orow0 = bm * 128 + wr * 64 + kq * 4;
    int ocol0 = bn * 128 + wc * 64 + r16;
    if constexpr (EPI == 5) {
        __shared__ float lnS[2][128], lnQ[2][128];
        float*  xg = (float*)outp;
        ushort* hg = (ushort*)outp2;
        // residual add (keep xnew in acc)
        #pragma unroll
        for (int ni = 0; ni < 4; ni++) {
            int col = ocol0 + ni * 16;          // N=128, bn=0 -> col = local col
            float bv = b2f(bias[col]);
            #pragma unroll
            for (int mi = 0; mi < 4; mi++) {
                #pragma unroll
                for (int e = 0; e < 4; e++) {
                    size_t gi = (size_t)(orow0 + mi * 16 + e) * 128 + col;
                    float xv = xg[gi] + acc[mi][ni][e] + bv;
                    xg[gi] = xv;
                    acc[mi][ni][e] = xv;
                }
            }
        }
        // per-row partials over this wave's 64 cols
        #pragma unroll
        for (int mi = 0; mi < 4; mi++) {
            #pragma unroll
            for (int e = 0; e < 4; e++) {
                float s = 0.f, q = 0.f;
                #pragma unroll
                for (int ni = 0; ni < 4; ni++) { float v = acc[mi][ni][e]; s += v; q += v * v; }
                #pragma unroll
                for (int mk = 1; mk < 16; mk <<= 1) {
                    s += __shfl_xor(s, mk, 64); q += __shfl_xor(q, mk, 64);
                }
                if (r16 == 0) {
                    int lrow = wr * 64 + mi * 16 + kq * 4 + e;
                    lnS[wc][lrow] = s; lnQ[wc][lrow] = q;
                }
            }
        }
        __syncthreads();
        float gc[4], bc[4];
        #pragma unroll
        for (int ni = 0; ni < 4; ni++) {
            int col = ocol0 + ni * 16;
            gc[ni] = b2f(lng[col]); bc[ni] = b2f(lnb[col]);
        }
        #pragma unroll
        for (int mi = 0; mi < 4; mi++) {
            #pragma unroll
            for (int e = 0; e < 4; e++) {
                int lrow = wr * 64 + mi * 16 + kq * 4 + e;
                float tot = lnS[0][lrow] + lnS[1][lrow];
                float tq  = lnQ[0][lrow] + lnQ[1][lrow];
                float mu  = tot * (1.0f / 128.0f);
                float var = tq * (1.0f / 128.0f) - mu * mu;
                float rstd = rsqrtf(var + 1e-5f);
                size_t grow = (size_t)(bm * 128 + lrow) * 128;
                #pragma unroll
                for (int ni = 0; ni < 4; ni++) {
                    int col = ocol0 + ni * 16;
                    hg[grow + col] = f2b((acc[mi][ni][e] - mu) * rstd * gc[ni] + bc[ni]);
                }
            }
        }
        return;
    }
    if constexpr (EPI == 4) {
        if (bn == 2) {
            ushort* vt = (ushort*)outp2;
            #pragma unroll
            for (int mi = 0; mi < 4; mi++) {
                int row0 = orow0 + mi * 16;
                int bb = row0 >> 9, tt = row0 & 511;
                #pragma unroll
                for (int ni = 0; ni < 4; ni++) {
                    int vd = (ocol0 - 256) + ni * 16;      // 0..127 = h*32 + d
                    int hh = vd >> 5, dd = vd & 31;
                    ushort4 pk;
                    pk.x = f2b(acc[mi][ni][0]); pk.y = f2b(acc[mi][ni][1]);
                    pk.z = f2b(acc[mi][ni][2]); pk.w = f2b(acc[mi][ni][3]);
                    *(ushort4*)(vt + (((size_t)(bb * 4 + hh) * 32 + dd) << 9) + tt) = pk;
                }
            }
            return;
        }
    }
    #pragma unroll
    for (int mi = 0; mi < 4; mi++) {
        #pragma unroll
        for (int ni = 0; ni < 4; ni++) {
            int col = ocol0 + ni * 16;
            float bv = 0.0f;
            if constexpr (EPI == 1 || EPI == 2) bv = b2f(bias[col]);
            #pragma unroll
            for (int e = 0; e < 4; e++) {
                int row = orow0 + mi * 16 + e;
                float v = acc[mi][ni][e] + bv;
                if constexpr (EPI == 2) v = 0.5f * v * (1.0f + erff(v * 0.70710678118f));
                if constexpr (EPI == 1) {
                    if (f32out) ((float*)outp)[(size_t)row * ldc + col] = v;
                    else        ((ushort*)outp)[(size_t)row * ldc + col] = f2b(v);
                } else {
                    ((ushort*)outp)[(size_t)row * ldc + col] = f2b(v);
                }
            }
        }
    }
}

// ---------------- MFMA flash attention, mirrored q-tile pairing --------------------
// qk: [M,256] bf16 (cols 0..127 q, 128..255 k); vt: [256 bh][32 d][512 t]; o: [M,128]
// Wave handles q-tiles iA and 31-iA (16 rows each) -> uniform causal work (~17 chunks),
// K/V loads shared in the overlap region. Swapped QK^T: lane owns q = lane&15;
// softmax stats reduced across the 4-lane q-group (xor 16,32).
constexpr float SC_ = 0.2550348637f;   // log2(e) / sqrt(32)

struct AST { f32x4 o0, o1; float m2, l; };

__device__ __forceinline__ void attn_step(AST& st, const f32x4& s0, const f32x4& s1,
                                          int j0, int myq, int r16, int g,
                                          const bf16x8& vf0, const bf16x8& vf1) {
    float sv[8];
    #pragma unroll
    for (int e = 0; e < 4; e++) {
        int ja = j0 + 4 * g + e;
        sv[e]     = (ja      <= myq) ? s0[e] * SC_ : -INFINITY;
        sv[4 + e] = (ja + 16 <= myq) ? s1[e] * SC_ : -INFINITY;
    }
    float pm = sv[0];
    #pragma unroll
    for (int i = 1; i < 8; i++) pm = fmaxf(pm, sv[i]);
    pm = fmaxf(pm, __shfl_xor(pm, 16, 64));
    pm = fmaxf(pm, __shfl_xor(pm, 32, 64));
    float mn = fmaxf(st.m2, pm);
    float c = exp2f(st.m2 - mn);
    float p[8], ps = 0.0f;
    #pragma unroll
    for (int i = 0; i < 8; i++) { p[i] = exp2f(sv[i] - mn); ps += p[i]; }
    ps += __shfl_xor(ps, 16, 64);
    ps += __shfl_xor(ps, 32, 64);
    st.l = st.l * c + ps;
    #pragma unroll
    for (int e = 0; e < 4; e++) { st.o0[e] *= c; st.o1[e] *= c; }
    st.m2 = mn;
    // P relayout: S^T C-layout -> B-fragment (lane g holds P[q=r16][j = g*8 .. g*8+8))
    uint pk00 = packbf(p[0], p[1]), pk01 = packbf(p[2], p[3]);
    uint pk10 = packbf(p[4], p[5]), pk11 = packbf(p[6], p[7]);
    int ga = ((g & 1) << 5) + r16;
    int gb = ga + 16;
    uint A0 = (uint)__shfl((int)pk00, ga), A1 = (uint)__shfl((int)pk01, ga);
    uint C0 = (uint)__shfl((int)pk00, gb), C1 = (uint)__shfl((int)pk01, gb);
    uint B0 = (uint)__shfl((int)pk10, ga), B1 = (uint)__shfl((int)pk11, ga);
    uint D0 = (uint)__shfl((int)pk10, gb), D1 = (uint)__shfl((int)pk11, gb);
    bool hi2 = g >= 2;
    uint4 pr;
    pr.x = hi2 ? B0 : A0; pr.y = hi2 ? B1 : A1;
    pr.z = hi2 ? D0 : C0; pr.w = hi2 ? D1 : C1;
    bf16x8 pf = __builtin_bit_cast(bf16x8, pr);
    st.o0 = __builtin_amdgcn_mfma_f32_16x16x32_bf16(vf0, pf, st.o0, 0, 0, 0);
    st.o1 = __builtin_amdgcn_mfma_f32_16x16x32_bf16(vf1, pf, st.o1, 0, 0, 0);
}

__global__ __launch_bounds__(256) void k_attn_mfma(const ushort* __restrict__ qk,
                                                   const ushort* __restrict__ vt,
                                                   ushort* __restrict__ o) {
    int lane = threadIdx.x & 63, w = threadIdx.x >> 6;
    int qs = blockIdx.x, bh = blockIdx.y;
    int b = bh >> 2, h = bh & 3;
    int r16 = lane & 15, g = lane >> 4;
    int iA = qs * 4 + w;                       // 0..15
    int qbaseA = iA * 16, qbaseB = (31 - iA) * 16;
    int myqA = qbaseA + r16, myqB = qbaseB + r16;
    int qmaxA = qbaseA + 15, qmaxB = qbaseB + 15;
    const ushort* qkbase = qk + (size_t)b * 512 * 256;
    bf16x8 qfA = *(const bf16x8*)(qkbase + (size_t)(qbaseA + r16) * 256 + h * 32 + g * 8);
    bf16x8 qfB = *(const bf16x8*)(qkbase + (size_t)(qbaseB + r16) * 256 + h * 32 + g * 8);
    const ushort* kptr = qkbase + 128 + h * 32 + g * 8;          // + j*256
    const ushort* vbase = vt + ((size_t)bh * 32) * 512;
    AST sA, sB;
    sA.o0 = (f32x4)0.0f; sA.o1 = (f32x4)0.0f; sA.m2 = -INFINITY; sA.l = 0.0f;
    sB = sA;
    for (int j0 = 0; j0 <= qmaxB; j0 += 32) {
        bf16x8 kf0 = *(const bf16x8*)(kptr + (size_t)(j0 + r16) * 256);
        bf16x8 kf1 = *(const bf16x8*)(kptr + (size_t)(j0 + 16 + r16) * 256);
        bf16x8 vf0 = *(const bf16x8*)(vbase + (size_t)r16 * 512 + j0 + g * 8);
        bf16x8 vf1 = *(const bf16x8*)(vbase + (size_t)(16 + r16) * 512 + j0 + g * 8);
        f32x4 b0 = __builtin_amdgcn_mfma_f32_16x16x32_bf16(kf0, qfB, (f32x4)0.0f, 0, 0, 0);
        f32x4 b1 = __builtin_amdgcn_mfma_f32_16x16x32_bf16(kf1, qfB, (f32x4)0.0f, 0, 0, 0);
        attn_step(sB, b0, b1, j0, myqB, r16, g, vf0, vf1);
        if (j0 <= qmaxA) {
            f32x4 a0 = __builtin_amdgcn_mfma_f32_16x16x32_bf16(kf0, qfA, (f32x4)0.0f, 0, 0, 0);
            f32x4 a1 = __builtin_amdgcn_mfma_f32_16x16x32_bf16(kf1, qfA, (f32x4)0.0f, 0, 0, 0);
            attn_step(sA, a0, a1, j0, myqA, r16, g, vf0, vf1);
        }
    }
    #pragma unroll
    for (int s = 0; s < 2; s++) {
        AST& st = s ? sB : sA;
        int qb = s ? qbaseB : qbaseA;
        float inv = 1.0f / st.l;
        ushort4 w0, w1;
        w0.x = f2b(st.o0[0] * inv); w0.y = f2b(st.o0[1] * inv);
        w0.z = f2b(st.o0[2] * inv); w0.w = f2b(st.o0[3] * inv);
        w1.x = f2b(st.o1[0] * inv); w1.y = f2b(st.o1[1] * inv);
        w1.z = f2b(st.o1[2] * inv); w1.w = f2b(st.o1[3] * inv);
        size_t orow = (size_t)(b * 512 + qb + r16) * 128 + h * 32;
        *(ushort4*)(o + orow + g * 4)      = w0;
        *(ushort4*)(o + orow + 16 + g * 4) = w1;
    }
}

extern "C" void kernel_launch(void* const* d_in, const int* in_sizes, int n_in,
                              void* d_out, int out_size, void* d_ws, size_t ws_size,
                              hipStream_t stream) {
    const int* idx = (const int*)d_in[0];

    // ws layout: x fp32 [0,16M); h bf16 [16M,24M); wqkvt [24M,+384K);
    //            arena bf16 [25M,+1.93M); flag int @ 27M.   (<28 MB total)
    char* ws = (char*)d_ws;
    float*  x     = (float*) (ws + 0);
    ushort* h     = (ushort*)(ws + (16u << 20));
    ushort* wqkvt = (ushort*)(ws + (24u << 20));
    ushort* arena = (ushort*)(ws + (25u << 20));
    int*    flag  = (int*)   (ws + (27u << 20));

    // d_out scratch (32MB): qk [M,256] bf16 @ [0,16M); o [M,128] @ [16M,24M);
    // vt [256][32][512] @ [24M,32M); mid [M,512] @ [0,32M) overlays all after attn+proj.
    ushort* qkv = (ushort*)d_out;
    ushort* o   = (ushort*)d_out + (8u << 20);
    ushort* vt  = (ushort*)d_out + (12u << 20);
    ushort* mid = (ushort*)d_out;

    const ushort* tok    = arena + kOffs[0];
    const ushort* pos    = arena + kOffs[1];
    const ushort* wqp    = arena + kOffs[2];
    const ushort* wkp    = arena + kOffs[3];
    const ushort* wvp    = arena + kOffs[4];
    const ushort* w_proj = arena + kOffs[5];
    const ushort* b_proj = arena + kOffs[6];
    const ushort* ln1_g  = arena + kOffs[7];
    const ushort* ln1_b  = arena + kOffs[8];
    const ushort* ln2_g  = arena + kOffs[9];
    const ushort* ln2_b  = arena + kOffs[10];
    const ushort* w1     = arena + kOffs[11];
    const ushort* b1     = arena + kOffs[12];
    const ushort* w2     = arena + kOffs[13];
    const ushort* b2     = arena + kOffs[14];
    const ushort* lnf_g  = arena + kOffs[15];
    const ushort* lnf_b  = arena + kOffs[16];
    const ushort* w_head = arena + kOffs[17];
    const ushort* b_head = arena + kOffs[18];

    k_detect<<<1, 64, 0, stream>>>((const uint*)d_in[8], flag);
    SrcPtrs sp;
    for (int i = 0; i < kNSeg; i++) sp.p[i] = d_in[i + 1];
    k_convert<<<(kTotal + 255) / 256, 256, 0, stream>>>(sp, flag, arena);

    k_prep_qkv<<<768, 256, 0, stream>>>(wqp, wkp, wvp, wqkvt);
    k_embed_ln<<<M_ / 4, 256, 0, stream>>>(idx, tok, pos, ln1_g, ln1_b, x, h);
    for (int l = 0; l < L_; l++) {
        const ushort* ng = (l < 3) ? (ln1_g + (l + 1) * E_) : lnf_g;
        const ushort* nb = (l < 3) ? (ln1_b + (l + 1) * E_) : lnf_b;
        k_gemm<4><<<dim3(M_ / 128, 3), 256, 0, stream>>>(h, wqkvt + (size_t)l * 384 * E_, nullptr,
                                                         qkv, vt, nullptr, nullptr, nullptr, 128, 128, 256);
        k_attn_mfma<<<dim3(4, 256), 256, 0, stream>>>(qkv, vt, o);
        k_gemm<5><<<dim3(M_ / 128, 1), 256, 0, stream>>>(o, w_proj + (size_t)l * E_ * E_, b_proj + l * E_,
                                                         x, h, ln2_g + l * E_, ln2_b + l * E_, nullptr, 128, 128, 128);
        k_gemm<2><<<dim3(M_ / 128, 4), 256, 0, stream>>>(h, w1 + (size_t)l * 4 * E_ * E_, b1 + l * 4 * E_,
                                                         mid, nullptr, nullptr, nullptr, nullptr, 128, 128, 512);
        k_gemm<5><<<dim3(M_ / 128, 1), 256, 0, stream>>>(mid, w2 + (size_t)l * E_ * 4 * E_, b2 + l * E_,
                                                         x, h, ng, nb, nullptr, 512, 512, 128);
    }
    k_gemm<1><<<dim3(M_ / 128, 4), 256, 0, stream>>>(h, w_head, b_head, d_out, nullptr,
                                                     nullptr, nullptr, flag, 128, 128, 512);
}